// Round 3
// baseline (207.991 us; speedup 1.0000x reference)
//
#include <hip/hip_runtime.h>
#include <math.h>

typedef unsigned char u8;
typedef __attribute__((ext_vector_type(4))) float floatx4;
typedef __attribute__((ext_vector_type(8))) int intx8;

#define B_ROWS 4096
#define D_DIM  256
#define C_CLS  20000
#define C_PAD  20096      // 157 tiles * 128 (tiles now 64 cols: 314 col-tiles, K-split below)
#define NTILE  157        // 157 tiles of 128 cols? -> now 64-col tiles: see TILE64
#define TILE64 314        // not used; we keep 157 tiles of 64 rows*256B = 16KB? see below
#define NSPLIT 64
#define TAIL_BLOCKS 64

// NOTE: W8 layout is row-major [C_PAD][256] fp8. A "tile" for gemm is now 64
// consecutive classes = 16 KB. C_PAD = 20096 = 314 * 64. Splits stride the
// 314 tiles by NSPLIT=64: sp gets tiles sp, sp+64, ... (4 or 5 tiles).
#define NT64 314

#define SC  43.280851227f   // 30 * log2(e)
#define M9  12.984255369f   // 9 * log2(e)
#define PRE 1.3525266f      // SC / 32: pre-scale E before fp8 so A-scale 2^5 folds SC in
#define SCL1 0x7f7f7f7f     // e8m0 == 127 -> scale 2^0 = 1.0 (all bytes)
#define SCA  0x84848484     // e8m0 == 132 -> scale 2^5 = 32 (all bytes)

// ---- RNE f32 -> OCP e4m3fn (software fallback; handles subnormals) ----
__device__ __forceinline__ u8 f32_to_e4m3_sw(float v) {
  unsigned u = __float_as_uint(v);
  unsigned s = (u >> 24) & 0x80u;
  float a = fabsf(v);
  if (a < 0.0009765625f) return (u8)s;
  unsigned ua = __float_as_uint(a);
  int ex = (int)(ua >> 23);
  if (ex < 121) ex = 121;
  float inv_step = __uint_as_float((unsigned)(257 - ex) << 23);
  float stepf    = __uint_as_float((unsigned)(ex - 3) << 23);
  float r = rintf(a * inv_step) * stepf;
  unsigned code;
  if (r == 0.0f) code = 0;
  else {
    unsigned ur = __float_as_uint(r);
    int er = (int)(ur >> 23) - 127;
    if (er < -6) code = (unsigned)(r * 512.0f);
    else code = ((unsigned)(er + 7) << 3) | ((ur >> 20) & 7u);
  }
  return (u8)(s | code);
}

// ---- pack 4 f32 -> 4x e4m3 bytes; HW cvt on gfx950 (OCP, RNE), 2 instrs ----
__device__ __forceinline__ unsigned pack4_e4m3(float a, float b, float c, float d) {
#if __has_builtin(__builtin_amdgcn_cvt_pk_fp8_f32)
  int v = 0;
  v = __builtin_amdgcn_cvt_pk_fp8_f32(a, b, v, false);  // low 16 bits
  v = __builtin_amdgcn_cvt_pk_fp8_f32(c, d, v, true);   // high 16 bits
  return (unsigned)v;
#else
  unsigned r = (unsigned)f32_to_e4m3_sw(a) | ((unsigned)f32_to_e4m3_sw(b) << 8) |
               ((unsigned)f32_to_e4m3_sw(c) << 16) | ((unsigned)f32_to_e4m3_sw(d) << 24);
  return r;
#endif
}

// ---- fused: normalize embeddings (f32 + pre-scaled fp8) + label cosine + bucket;
//      weights (fp8, unit scale) ----
__global__ void normalize_all(const float* __restrict__ emb, const float* __restrict__ wgt,
                              const int* __restrict__ labels,
                              float* __restrict__ En, u8* __restrict__ E8,
                              u8* __restrict__ W8, float* __restrict__ lcos,
                              int* __restrict__ cnt_i, int* __restrict__ members) {
  const int r = blockIdx.x * 4 + (threadIdx.x >> 6);
  const int lane = threadIdx.x & 63;
  if (r < B_ROWS) {
    float4 v = ((const float4*)(emb + (size_t)r * D_DIM))[lane];
    float ss = v.x * v.x + v.y * v.y + v.z * v.z + v.w * v.w;
    for (int m = 1; m < 64; m <<= 1) ss += __shfl_xor(ss, m);
    float k = 1.0f / sqrtf(ss);
    v.x *= k; v.y *= k; v.z *= k; v.w *= k;
    ((float4*)(En + (size_t)r * D_DIM))[lane] = v;   // exact unit-norm rows (tail + lcos)
    ((unsigned*)(E8 + (size_t)r * D_DIM))[lane] =
        pack4_e4m3(v.x * PRE, v.y * PRE, v.z * PRE, v.w * PRE);
    // label cosine in f32 (exact margin/label terms later)
    int lab = labels[r];
    float4 wv = ((const float4*)(wgt + (size_t)lab * D_DIM))[lane];
    float dot = v.x * wv.x + v.y * wv.y + v.z * wv.z + v.w * wv.w;
    float ws = wv.x * wv.x + wv.y * wv.y + wv.z * wv.z + wv.w * wv.w;
    for (int m = 1; m < 64; m <<= 1) {
      dot += __shfl_xor(dot, m);
      ws += __shfl_xor(ws, m);
    }
    if (lane == 0) {
      lcos[r] = dot / sqrtf(ws);
      int p = atomicAdd(&cnt_i[lab], 1);
      if (p < 16) members[lab * 16 + p] = r;
    }
  } else {
    int wr_ = r - B_ROWS;
    if (wr_ >= C_CLS) {
      ((unsigned*)(W8 + (size_t)wr_ * D_DIM))[lane] = 0u;
      return;
    }
    float4 v = ((const float4*)(wgt + (size_t)wr_ * D_DIM))[lane];
    float ss = v.x * v.x + v.y * v.y + v.z * v.z + v.w * v.w;
    for (int m = 1; m < 64; m <<= 1) ss += __shfl_xor(ss, m);
    float k = 1.0f / sqrtf(ss);
    ((unsigned*)(W8 + (size_t)wr_ * D_DIM))[lane] =
        pack4_e4m3(v.x * k, v.y * k, v.z * k, v.w * k);
  }
}

// ---- MX-fp8 cosine GEMM + exp-sum; M=256 rows x 64-col tiles, DMA double-buffer ----
// grid (16 row-tiles, 64 splits) = 1024 blocks = 4 blocks/CU (LDS 32KB, VGPR<=128).
// Occupancy probe: 2 -> 4 blocks/CU for latency hiding.
// SC folded into MFMA: A-scale=2^5 (E pre-scaled by SC/32), C init = -SC.
// Swizzle: slot = chunk ^ (row & 14): chunk pairs stay adjacent for every lane
//   -> B fragment is ONE aligned 32B LDS read (2-way bank conflict = free, m136).
// Output: global atomicAdd into row_S[4096] (zeroed in memset) - no slabs.
__global__ __launch_bounds__(256, 4) void gemm_softmax(
    const u8* __restrict__ E8, const u8* __restrict__ W8,
    float* __restrict__ row_S) {
  __shared__ char lds[32768];   // 2 x 16 KB
  const int tid = threadIdx.x;
  const int lane = tid & 63, w = tid >> 6;
  const int quad = lane >> 4, c16 = lane & 15;
  const int rt = blockIdx.x, sp = blockIdx.y;
  const int wr = w * 64;   // 4 waves x 64 rows = 256 rows

  // staging: granule g=i*256+tid -> row n=g>>4, slot g&15 holds src chunk (g&15)^(n&14)
  const int stageSrc = ((tid >> 4) << 8) + (((tid & 15) ^ ((tid >> 4) & 14)) << 4);
  auto stage = [&](int buf, int t) {
    const char* src = (const char*)W8 + (size_t)t * 16384 + stageSrc;
    char* dst = lds + buf * 16384 + tid * 16;
#pragma unroll
    for (int i = 0; i < 4; ++i)
      __builtin_amdgcn_global_load_lds(
          (const __attribute__((address_space(1))) unsigned int*)(src + i * 4096),
          (__attribute__((address_space(3))) unsigned int*)(dst + i * 4096), 16, 0, 0);
  };

  stage(0, sp);   // prefetch first tile (async)

  // A fragments direct from global: row m=c16(+16mt+wr), k = kk*128 + quad*32 + byte
  intx8 a[4][2];
#pragma unroll
  for (int mt = 0; mt < 4; ++mt) {
    const u8* rp = E8 + ((size_t)(rt * 256 + wr + mt * 16 + c16)) * 256 + quad * 32;
#pragma unroll
    for (int kk = 0; kk < 2; ++kk)
      a[mt][kk] = *(const intx8*)(rp + kk * 128);
  }

  // B read offsets: chunk pair base g=kk*8+quad*2 at slot g^(c16&14), 32B contiguous
  int oA[2];
#pragma unroll
  for (int kk = 0; kk < 2; ++kk)
    oA[kk] = (((kk * 8 + quad * 2) ^ (c16 & 14)) << 4);

  float run_s[4][4] = {};
  __syncthreads();   // first tile staged (barrier drains vmcnt)
  int cur = 0;
  for (int t = sp; t < NT64; t += NSPLIT) {
    int tn = t + NSPLIT;
    if (tn < NT64) stage(cur ^ 1, tn);   // in flight through the MFMA phase
    const char* bbase = lds + cur * 16384 + c16 * 256;
#pragma unroll
    for (int nt = 0; nt < 4; ++nt) {
      intx8 bv[2];
#pragma unroll
      for (int kk = 0; kk < 2; ++kk)
        bv[kk] = *(const intx8*)(bbase + nt * 4096 + oA[kk]);
      floatx4 acc[4];
#pragma unroll
      for (int mt = 0; mt < 4; ++mt)
        acc[mt] = (floatx4){-SC, -SC, -SC, -SC};   // C-init folds the -SC
      __builtin_amdgcn_s_setprio(1);               // favor MFMA-issuing wave (T5)
#pragma unroll
      for (int kk = 0; kk < 2; ++kk)
#pragma unroll
        for (int mt = 0; mt < 4; ++mt)
          acc[mt] = __builtin_amdgcn_mfma_scale_f32_16x16x128_f8f6f4(
              a[mt][kk], bv[kk], acc[mt], 0, 0, 0, SCA, 0, SCL1);
      __builtin_amdgcn_s_setprio(0);
#pragma unroll
      for (int mt = 0; mt < 4; ++mt)
#pragma unroll
        for (int rg = 0; rg < 4; ++rg)
          run_s[mt][rg] += __builtin_amdgcn_exp2f(acc[mt][rg]);
    }
    __syncthreads();   // waves done reading cur; prefetch into cur^1 drained
    cur ^= 1;
  }
  // reduce across 16 column lanes; atomic into row_S (32 splits -> 16-way per addr)
#pragma unroll
  for (int mt = 0; mt < 4; ++mt)
#pragma unroll
    for (int rg = 0; rg < 4; ++rg) {
      float s = run_s[mt][rg];
      s += __shfl_xor(s, 1);
      s += __shfl_xor(s, 2);
      s += __shfl_xor(s, 4);
      s += __shfl_xor(s, 8);
      if (c16 == 0)
        atomicAdd(&row_S[rt * 256 + wr + mt * 16 + quad * 4 + rg], s);
    }
}

// ---- tail: intra loss (closed form, wave-per-class) + AM row terms,
//      wave shuffle-reduce + 16-entry cross-wave LDS -> 3 atomics/block, ticket combine ----
__global__ __launch_bounds__(1024) void tail(
    const int* __restrict__ cnt_i, const int* __restrict__ members,
    const float* __restrict__ En, const float* __restrict__ row_S,
    const float* __restrict__ lcos, float* __restrict__ pgnv,
    float* __restrict__ out) {
  __shared__ float red[16][3];
  const int t = threadIdx.x, blk = blockIdx.x;
  const int gtid = blk * 1024 + t;
  const int lane = t & 63;
  const int wid = t >> 6;     // wave in block, 0..15
  const int gw = gtid >> 6;   // global wave id, 0..1023

  // --- intra: each wave scans classes gw, gw+1024, ... (closed form) ---
  float pg = 0.0f, nv = 0.0f;
  for (int c = gw; c < C_CLS; c += 1024) {
    int m = cnt_i[c];                 // same addr across wave -> broadcast
    if (m < 2) continue;
    if (m > 16) m = 16;
    float4 S = {0.0f, 0.0f, 0.0f, 0.0f};
    for (int r = 0; r < m; ++r) {
      int row = members[c * 16 + r];
      float4 v = ((const float4*)(En + (size_t)row * D_DIM))[lane];
      S.x += v.x; S.y += v.y; S.z += v.z; S.w += v.w;
    }
    float ss = S.x * S.x + S.y * S.y + S.z * S.z + S.w * S.w;
    for (int k = 1; k < 64; k <<= 1) ss += __shfl_xor(ss, k);
    if (lane == 0) {
      // sum_{r<s}(1 - e_r.e_s) = C(m,2) - (|sum e|^2 - m)/2  (unit-norm rows)
      float fm = (float)m;
      float np = 0.5f * fm * (fm - 1.0f);
      float dsum = np - 0.5f * (ss - fm);
      pg += fmaxf(dsum / np - 0.5f, 0.0f);
      nv += 1.0f;
    }
  }

  // --- AM: thread-per-row; row_S already holds the full split-summed exp-sum ---
  const float padc = 96.0f * __builtin_amdgcn_exp2f(-SC);  // pad classes: cos==0 exactly
  float nlp = 0.0f;
  for (int r = gtid; r < B_ROWS; r += TAIL_BLOCKS * 1024) {
    float c = lcos[r];
    float S = row_S[r] - padc
            + __builtin_amdgcn_exp2f(fmaf(SC, c, -SC - M9))   // margined label term
            - __builtin_amdgcn_exp2f(fmaf(SC, c, -SC));       // remove unmargined label term
    nlp += 30.0f + logf(S) - fmaf(30.0f, c, -9.0f);
  }

  // --- block reduce (pg, nv, nlp): wave shuffle + 16-entry LDS, 1 barrier ---
  float vals[3] = {pg, nv, nlp};
#pragma unroll
  for (int q = 0; q < 3; ++q)
#pragma unroll
    for (int m = 1; m < 64; m <<= 1) vals[q] += __shfl_xor(vals[q], m);
  if (lane == 0) {
    red[wid][0] = vals[0]; red[wid][1] = vals[1]; red[wid][2] = vals[2];
  }
  __syncthreads();
  if (t == 0) {
    float b0 = 0.0f, b1 = 0.0f, b2 = 0.0f;
#pragma unroll
    for (int i = 0; i < 16; ++i) {
      b0 += red[i][0]; b1 += red[i][1]; b2 += red[i][2];
    }
    atomicAdd(&pgnv[0], b0);
    atomicAdd(&pgnv[1], b1);
    atomicAdd(&pgnv[2], b2);
    __threadfence();
    unsigned ticket = atomicAdd((unsigned*)&pgnv[3], 1u);
    if (ticket == TAIL_BLOCKS - 1) {   // last block: all adds device-visible
      float pgT = atomicAdd(&pgnv[0], 0.0f);
      float nvT = atomicAdd(&pgnv[1], 0.0f);
      float nlT = atomicAdd(&pgnv[2], 0.0f);
      float am = nlT * (1.0f / (float)B_ROWS);
      float intra = (nvT > 0.0f) ? (pgT / nvT) : 0.0f;
      out[0] = am + 0.1f * intra;
      out[1] = am;
      out[2] = intra;
    }
  }
}

extern "C" void kernel_launch(void* const* d_in, const int* in_sizes, int n_in,
                              void* d_out, int out_size, void* d_ws, size_t ws_size,
                              hipStream_t stream) {
  const float* emb = (const float*)d_in[0];
  const int* labels = (const int*)d_in[1];
  const float* weight = (const float*)d_in[2];
  float* out = (float*)d_out;
  char* ws = (char*)d_ws;

  float* En      = (float*)(ws);               //  4,194,304
  u8*    E8      = (u8*)(ws + 4194304);        //  1,048,576 ->  5,242,880
  u8*    W8      = (u8*)(ws + 5242880);        //  5,144,576 -> 10,387,456
  int*   cnt_i   = (int*)(ws + 10387456);      //     80,000 -> 10,467,456
  float* pgnv    = (float*)(ws + 10467456);    //         16 -> 10,467,472
  float* row_S   = (float*)(ws + 10467472);    //     16,384 -> 10,483,856
  float* lcos    = (float*)(ws + 10483856);    //     16,384 -> 10,500,240
  int*   members = (int*)(ws + 10500240);      //  1,280,000 -> 11,780,240

  hipMemsetAsync(ws + 10387456, 0, 96400, stream);  // cnt_i + pgnv(+ticket) + row_S
  normalize_all<<<(B_ROWS + C_PAD) / 4, 256, 0, stream>>>(emb, weight, labels, En, E8, W8,
                                                          lcos, cnt_i, members);
  gemm_softmax<<<dim3(16, NSPLIT), 256, 0, stream>>>(E8, W8, row_S);
  tail<<<TAIL_BLOCKS, 1024, 0, stream>>>(cnt_i, members, En, row_S, lcos, pgnv, out);
}

// Round 4
// 115.986 us; speedup vs baseline: 1.7932x; 1.7932x over previous
//
#include <hip/hip_runtime.h>
#include <math.h>

typedef unsigned char u8;
typedef __attribute__((ext_vector_type(4))) float floatx4;
typedef __attribute__((ext_vector_type(8))) int intx8;

#define B_ROWS 4096
#define D_DIM  256
#define C_CLS  20000
#define C_PAD  20096      // 157 tiles * 128 cols
#define NTILE  157
#define NSPLIT 32
#define TAIL_BLOCKS 64

#define SC  43.280851227f   // 30 * log2(e)
#define M9  12.984255369f   // 9 * log2(e)
#define PRE 1.3525266f      // SC / 32: pre-scale E before fp8 so A-scale 2^5 folds SC in
#define SCL1 0x7f7f7f7f     // e8m0 == 127 -> scale 2^0 = 1.0 (all bytes)
#define SCA  0x84848484     // e8m0 == 132 -> scale 2^5 = 32 (all bytes)

// ---- RNE f32 -> OCP e4m3fn (software fallback; handles subnormals) ----
__device__ __forceinline__ u8 f32_to_e4m3_sw(float v) {
  unsigned u = __float_as_uint(v);
  unsigned s = (u >> 24) & 0x80u;
  float a = fabsf(v);
  if (a < 0.0009765625f) return (u8)s;
  unsigned ua = __float_as_uint(a);
  int ex = (int)(ua >> 23);
  if (ex < 121) ex = 121;
  float inv_step = __uint_as_float((unsigned)(257 - ex) << 23);
  float stepf    = __uint_as_float((unsigned)(ex - 3) << 23);
  float r = rintf(a * inv_step) * stepf;
  unsigned code;
  if (r == 0.0f) code = 0;
  else {
    unsigned ur = __float_as_uint(r);
    int er = (int)(ur >> 23) - 127;
    if (er < -6) code = (unsigned)(r * 512.0f);
    else code = ((unsigned)(er + 7) << 3) | ((ur >> 20) & 7u);
  }
  return (u8)(s | code);
}

// ---- pack 4 f32 -> 4x e4m3 bytes; HW cvt on gfx950 (OCP, RNE), 2 instrs ----
__device__ __forceinline__ unsigned pack4_e4m3(float a, float b, float c, float d) {
#if __has_builtin(__builtin_amdgcn_cvt_pk_fp8_f32)
  int v = 0;
  v = __builtin_amdgcn_cvt_pk_fp8_f32(a, b, v, false);  // low 16 bits
  v = __builtin_amdgcn_cvt_pk_fp8_f32(c, d, v, true);   // high 16 bits
  return (unsigned)v;
#else
  unsigned r = (unsigned)f32_to_e4m3_sw(a) | ((unsigned)f32_to_e4m3_sw(b) << 8) |
               ((unsigned)f32_to_e4m3_sw(c) << 16) | ((unsigned)f32_to_e4m3_sw(d) << 24);
  return r;
#endif
}

// ---- fused: normalize embeddings (f32 + pre-scaled fp8) + label cosine + bucket;
//      weights (fp8, unit scale) ----
__global__ void normalize_all(const float* __restrict__ emb, const float* __restrict__ wgt,
                              const int* __restrict__ labels,
                              float* __restrict__ En, u8* __restrict__ E8,
                              u8* __restrict__ W8, float* __restrict__ lcos,
                              int* __restrict__ cnt_i, int* __restrict__ members) {
  const int r = blockIdx.x * 4 + (threadIdx.x >> 6);
  const int lane = threadIdx.x & 63;
  if (r < B_ROWS) {
    float4 v = ((const float4*)(emb + (size_t)r * D_DIM))[lane];
    float ss = v.x * v.x + v.y * v.y + v.z * v.z + v.w * v.w;
    for (int m = 1; m < 64; m <<= 1) ss += __shfl_xor(ss, m);
    float k = 1.0f / sqrtf(ss);
    v.x *= k; v.y *= k; v.z *= k; v.w *= k;
    ((float4*)(En + (size_t)r * D_DIM))[lane] = v;   // exact unit-norm rows (tail + lcos)
    ((unsigned*)(E8 + (size_t)r * D_DIM))[lane] =
        pack4_e4m3(v.x * PRE, v.y * PRE, v.z * PRE, v.w * PRE);
    // label cosine in f32 (exact margin/label terms later)
    int lab = labels[r];
    float4 wv = ((const float4*)(wgt + (size_t)lab * D_DIM))[lane];
    float dot = v.x * wv.x + v.y * wv.y + v.z * wv.z + v.w * wv.w;
    float ws = wv.x * wv.x + wv.y * wv.y + wv.z * wv.z + wv.w * wv.w;
    for (int m = 1; m < 64; m <<= 1) {
      dot += __shfl_xor(dot, m);
      ws += __shfl_xor(ws, m);
    }
    if (lane == 0) {
      lcos[r] = dot / sqrtf(ws);
      int p = atomicAdd(&cnt_i[lab], 1);
      if (p < 16) members[lab * 16 + p] = r;
    }
  } else {
    int wr_ = r - B_ROWS;
    if (wr_ >= C_CLS) {
      ((unsigned*)(W8 + (size_t)wr_ * D_DIM))[lane] = 0u;
      return;
    }
    float4 v = ((const float4*)(wgt + (size_t)wr_ * D_DIM))[lane];
    float ss = v.x * v.x + v.y * v.y + v.z * v.z + v.w * v.w;
    for (int m = 1; m < 64; m <<= 1) ss += __shfl_xor(ss, m);
    float k = 1.0f / sqrtf(ss);
    ((unsigned*)(W8 + (size_t)wr_ * D_DIM))[lane] =
        pack4_e4m3(v.x * k, v.y * k, v.z * k, v.w * k);
  }
}

// ---- MX-fp8 cosine GEMM + exp-sum; M=256 x N=128 tiles, DMA double-buffer ----
// R4: 512-thr blocks (8 waves x 32 rows) -> a[2][2] = 32 VGPR (live set ~90,
// no spill under the 128 cap), LDS 2x32KB = 64KB -> 2 blocks/CU = 16 waves/CU
// (double R2's occupancy, which measured ~31 us vs a 9 us MFMA floor).
// SC folded into MFMA: A-scale=2^5 (E pre-scaled by SC/32), C init = -SC.
// Swizzle: slot = chunk ^ (row & 14): chunk pairs adjacent -> one 32B LDS read
// per B fragment (2-way bank conflict = free, m136).
// Output: global atomicAdd into row_S[4096] (zeroed in memset).
__global__ __launch_bounds__(512, 4) void gemm_softmax(
    const u8* __restrict__ E8, const u8* __restrict__ W8,
    float* __restrict__ row_S) {
  __shared__ char lds[65536];   // 2 x 32 KB
  const int tid = threadIdx.x;
  const int lane = tid & 63, w = tid >> 6;          // 8 waves
  const int quad = lane >> 4, c16 = lane & 15;
  const int rt = blockIdx.x, sp = blockIdx.y;
  const int wr = w * 32;   // 8 waves x 32 rows = 256 rows

  // staging: granule g = i*512 + tid (16B); row n = g>>4 = i*32 + (tid>>4);
  // dst slot g&15 = tid&15 holds src chunk (tid&15) ^ (n&14); n&15 == (tid>>4)&15.
  const int stageSrc = ((tid >> 4) << 8) + (((tid & 15) ^ ((tid >> 4) & 14)) << 4);
  auto stage = [&](int buf, int t) {
    const char* src = (const char*)W8 + (size_t)t * 32768 + stageSrc;
    char* dst = lds + buf * 32768 + tid * 16;
#pragma unroll
    for (int i = 0; i < 4; ++i)
      __builtin_amdgcn_global_load_lds(
          (const __attribute__((address_space(1))) unsigned int*)(src + i * 8192),
          (__attribute__((address_space(3))) unsigned int*)(dst + i * 8192), 16, 0, 0);
  };

  stage(0, sp);   // prefetch first tile (async)

  // A fragments direct from global: row m = rt*256 + wr + mt*16 + c16,
  // k = kk*128 + quad*32 + byte. 2 mt x 2 kk x 32B = 32 VGPRs.
  intx8 a[2][2];
#pragma unroll
  for (int mt = 0; mt < 2; ++mt) {
    const u8* rp = E8 + ((size_t)(rt * 256 + wr + mt * 16 + c16)) * 256 + quad * 32;
#pragma unroll
    for (int kk = 0; kk < 2; ++kk)
      a[mt][kk] = *(const intx8*)(rp + kk * 128);
  }

  // B read offsets: chunk pair base g = kk*8 + quad*2 at slot g^(c16&14), 32B contiguous
  int oA[2];
#pragma unroll
  for (int kk = 0; kk < 2; ++kk)
    oA[kk] = (((kk * 8 + quad * 2) ^ (c16 & 14)) << 4);

  float run_s[2][4] = {};
  __syncthreads();   // first tile staged (barrier drains vmcnt)
  int cur = 0;
  for (int t = sp; t < NTILE; t += NSPLIT) {
    int tn = t + NSPLIT;
    if (tn < NTILE) stage(cur ^ 1, tn);   // in flight through the MFMA phase
    const char* bbase = lds + cur * 32768 + c16 * 256;
#pragma unroll
    for (int nt = 0; nt < 8; ++nt) {
      intx8 bv[2];
#pragma unroll
      for (int kk = 0; kk < 2; ++kk)
        bv[kk] = *(const intx8*)(bbase + nt * 4096 + oA[kk]);
      floatx4 acc[2];
#pragma unroll
      for (int mt = 0; mt < 2; ++mt)
        acc[mt] = (floatx4){-SC, -SC, -SC, -SC};   // C-init folds the -SC
      __builtin_amdgcn_s_setprio(1);               // favor MFMA-issuing wave (T5)
#pragma unroll
      for (int kk = 0; kk < 2; ++kk)
#pragma unroll
        for (int mt = 0; mt < 2; ++mt)
          acc[mt] = __builtin_amdgcn_mfma_scale_f32_16x16x128_f8f6f4(
              a[mt][kk], bv[kk], acc[mt], 0, 0, 0, SCA, 0, SCL1);
      __builtin_amdgcn_s_setprio(0);
#pragma unroll
      for (int mt = 0; mt < 2; ++mt)
#pragma unroll
        for (int rg = 0; rg < 4; ++rg)
          run_s[mt][rg] += __builtin_amdgcn_exp2f(acc[mt][rg]);
    }
    __syncthreads();   // waves done reading cur; prefetch into cur^1 drained
    cur ^= 1;
  }
  // reduce across 16 column lanes; atomic into row_S (32 splits -> 32 adds/addr)
#pragma unroll
  for (int mt = 0; mt < 2; ++mt)
#pragma unroll
    for (int rg = 0; rg < 4; ++rg) {
      float s = run_s[mt][rg];
      s += __shfl_xor(s, 1);
      s += __shfl_xor(s, 2);
      s += __shfl_xor(s, 4);
      s += __shfl_xor(s, 8);
      if (c16 == 0)
        atomicAdd(&row_S[rt * 256 + wr + mt * 16 + quad * 4 + rg], s);
    }
}

// ---- tail: intra loss (closed form, wave-per-class) + AM row terms,
//      wave shuffle-reduce + 16-entry cross-wave LDS -> 3 atomics/block, ticket combine ----
__global__ __launch_bounds__(1024) void tail(
    const int* __restrict__ cnt_i, const int* __restrict__ members,
    const float* __restrict__ En, const float* __restrict__ row_S,
    const float* __restrict__ lcos, float* __restrict__ pgnv,
    float* __restrict__ out) {
  __shared__ float red[16][3];
  const int t = threadIdx.x, blk = blockIdx.x;
  const int gtid = blk * 1024 + t;
  const int lane = t & 63;
  const int wid = t >> 6;     // wave in block, 0..15
  const int gw = gtid >> 6;   // global wave id, 0..1023

  // --- intra: each wave scans classes gw, gw+1024, ... (closed form) ---
  float pg = 0.0f, nv = 0.0f;
  for (int c = gw; c < C_CLS; c += 1024) {
    int m = cnt_i[c];                 // same addr across wave -> broadcast
    if (m < 2) continue;
    if (m > 16) m = 16;
    float4 S = {0.0f, 0.0f, 0.0f, 0.0f};
    for (int r = 0; r < m; ++r) {
      int row = members[c * 16 + r];
      float4 v = ((const float4*)(En + (size_t)row * D_DIM))[lane];
      S.x += v.x; S.y += v.y; S.z += v.z; S.w += v.w;
    }
    float ss = S.x * S.x + S.y * S.y + S.z * S.z + S.w * S.w;
    for (int k = 1; k < 64; k <<= 1) ss += __shfl_xor(ss, k);
    if (lane == 0) {
      // sum_{r<s}(1 - e_r.e_s) = C(m,2) - (|sum e|^2 - m)/2  (unit-norm rows)
      float fm = (float)m;
      float np = 0.5f * fm * (fm - 1.0f);
      float dsum = np - 0.5f * (ss - fm);
      pg += fmaxf(dsum / np - 0.5f, 0.0f);
      nv += 1.0f;
    }
  }

  // --- AM: thread-per-row; row_S already holds the full split-summed exp-sum ---
  const float padc = 96.0f * __builtin_amdgcn_exp2f(-SC);  // pad classes: cos==0 exactly
  float nlp = 0.0f;
  for (int r = gtid; r < B_ROWS; r += TAIL_BLOCKS * 1024) {
    float c = lcos[r];
    float S = row_S[r] - padc
            + __builtin_amdgcn_exp2f(fmaf(SC, c, -SC - M9))   // margined label term
            - __builtin_amdgcn_exp2f(fmaf(SC, c, -SC));       // remove unmargined label term
    nlp += 30.0f + logf(S) - fmaf(30.0f, c, -9.0f);
  }

  // --- block reduce (pg, nv, nlp): wave shuffle + 16-entry LDS, 1 barrier ---
  float vals[3] = {pg, nv, nlp};
#pragma unroll
  for (int q = 0; q < 3; ++q)
#pragma unroll
    for (int m = 1; m < 64; m <<= 1) vals[q] += __shfl_xor(vals[q], m);
  if (lane == 0) {
    red[wid][0] = vals[0]; red[wid][1] = vals[1]; red[wid][2] = vals[2];
  }
  __syncthreads();
  if (t == 0) {
    float b0 = 0.0f, b1 = 0.0f, b2 = 0.0f;
#pragma unroll
    for (int i = 0; i < 16; ++i) {
      b0 += red[i][0]; b1 += red[i][1]; b2 += red[i][2];
    }
    atomicAdd(&pgnv[0], b0);
    atomicAdd(&pgnv[1], b1);
    atomicAdd(&pgnv[2], b2);
    __threadfence();
    unsigned ticket = atomicAdd((unsigned*)&pgnv[3], 1u);
    if (ticket == TAIL_BLOCKS - 1) {   // last block: all adds device-visible
      float pgT = atomicAdd(&pgnv[0], 0.0f);
      float nvT = atomicAdd(&pgnv[1], 0.0f);
      float nlT = atomicAdd(&pgnv[2], 0.0f);
      float am = nlT * (1.0f / (float)B_ROWS);
      float intra = (nvT > 0.0f) ? (pgT / nvT) : 0.0f;
      out[0] = am + 0.1f * intra;
      out[1] = am;
      out[2] = intra;
    }
  }
}

extern "C" void kernel_launch(void* const* d_in, const int* in_sizes, int n_in,
                              void* d_out, int out_size, void* d_ws, size_t ws_size,
                              hipStream_t stream) {
  const float* emb = (const float*)d_in[0];
  const int* labels = (const int*)d_in[1];
  const float* weight = (const float*)d_in[2];
  float* out = (float*)d_out;
  char* ws = (char*)d_ws;

  float* En      = (float*)(ws);               //  4,194,304
  u8*    E8      = (u8*)(ws + 4194304);        //  1,048,576 ->  5,242,880
  u8*    W8      = (u8*)(ws + 5242880);        //  5,144,576 -> 10,387,456
  int*   cnt_i   = (int*)(ws + 10387456);      //     80,000 -> 10,467,456
  float* pgnv    = (float*)(ws + 10467456);    //         16 -> 10,467,472
  float* row_S   = (float*)(ws + 10467472);    //     16,384 -> 10,483,856
  float* lcos    = (float*)(ws + 10483856);    //     16,384 -> 10,500,240
  int*   members = (int*)(ws + 10500240);      //  1,280,000 -> 11,780,240

  hipMemsetAsync(ws + 10387456, 0, 96400, stream);  // cnt_i + pgnv(+ticket) + row_S
  normalize_all<<<(B_ROWS + C_PAD) / 4, 256, 0, stream>>>(emb, weight, labels, En, E8, W8,
                                                          lcos, cnt_i, members);
  gemm_softmax<<<dim3(16, NSPLIT), 512, 0, stream>>>(E8, W8, row_S);
  tail<<<TAIL_BLOCKS, 1024, 0, stream>>>(cnt_i, members, En, row_S, lcos, pgnv, out);
}